// Round 9
// baseline (973.809 us; speedup 1.0000x reference)
//
#include <hip/hip_runtime.h>

typedef unsigned int u32;
typedef unsigned short u16;
typedef unsigned char u8;

#define NFR 8
#define NBX 1024
#define NTOT 8192     // 8*1024
#define NROW 7168     // 7*1024 adjacency rows
#define MAXS 48
#define NEGV -1000000000.0f
#define OVTOT 128     // listed-overflow slot budget
#define PSTRIDE 64    // global pool u16 per row: [deg, j0..], deg<=63
#define LPOOLCAP 1344 // u16 entries in the LDS pool (overlays class bitplanes)
#define DEG_RECOMP 0xFFFF
#define ENC_PENDING ((3u << 30) | (1022u << 10) | 1022u)
#define ENC_RESCAN  ((3u << 30) | (1023u << 10) | 1023u)

// Exact predicate IoU(a,b) >= 0.2 in f32, _rn ops in the reference's
// association order so -ffp-contract cannot change any compare vs numpy.
// LINKAGE_T == IOU_T == 0.2: one predicate serves both uses.
__device__ __forceinline__ bool iou_ge(float4 a, float4 b) {
    float wx = fmaxf(__fsub_rn(fminf(a.z, b.z), fmaxf(a.x, b.x)), 0.0f);
    float wy = fmaxf(__fsub_rn(fminf(a.w, b.w), fmaxf(a.y, b.y)), 0.0f);
    float inter = __fmul_rn(wx, wy);
    if (!(inter > 0.0f)) return false;      // iou == 0 can never pass >= 0.2
    float aa = __fmul_rn(__fsub_rn(a.z, a.x), __fsub_rn(a.w, a.y));
    float ab = __fmul_rn(__fsub_rn(b.z, b.x), __fsub_rn(b.w, b.y));
    float den = __fadd_rn(__fsub_rn(__fadd_rn(aa, ab), inter), 1e-8f);
    return __fdiv_rn(inter, den) >= 0.2f;
}

// ---- cold helpers, kept out of the hot instruction stream ----

// Exact serial rescan of one row (only when slot budget exhausted: ~never).
__device__ __attribute__((noinline))
float rescan_best(const u32* clsb_f, const float* msn, const float4* gboxn,
                  int ca, float4 a4) {
    float best = 0.0f;
    for (int w = 0; w < 32; ++w) {
        u32 q0 = clsb_f[w], q1 = clsb_f[32 + w], q2 = clsb_f[64 + w];
        u32 m = ((ca & 1) ? q0 : ~q0) & ((ca & 2) ? q1 : ~q1) & ((ca & 4) ? q2 : ~q2);
        while (m) {
            int b = __ffs(m) - 1;
            m &= m - 1;
            int j = w * 32 + b;
            float mv = msn[j];
            if (mv > 0.0f && iou_ge(a4, gboxn[j])) best = fmaxf(best, mv);
        }
    }
    return best;
}

// Phase B when the LDS pool is unavailable: round-8 global-pool / recompute.
__device__ __attribute__((noinline))
void phaseB_slow(int f, float* ms, const float* msn, const u16* ovl,
                 const u8* ovact, const u32* clsbpool, const u16* poolG,
                 const float* scores, const int* classes, const float4* gbox,
                 int s0, int s1, int gw, int ln, int use_pool) {
    for (int s = s0 + gw; s < s1; s += 16) {
        int i = ovl[s];
        int rr = f * NBX + i;
        bool actv = ovact[s] != 0;
        float best = 0.0f;
        if (actv) {
            int deg = use_pool ? (int)poolG[s * PSTRIDE] : (int)DEG_RECOMP;
            if (deg != (int)DEG_RECOMP) {
                for (int q = ln; q < deg; q += 64)
                    best = fmaxf(best, fmaxf(msn[poolG[s * PSTRIDE + 1 + q]], 0.0f));
            } else if (ln < 32) {
                int ca = classes[rr];
                float4 a4 = gbox[rr];
                const u32* cf = &clsbpool[f * 96];
                u32 q0 = cf[ln], q1 = cf[32 + ln], q2 = cf[64 + ln];
                u32 m = ((ca & 1) ? q0 : ~q0) & ((ca & 2) ? q1 : ~q1) & ((ca & 4) ? q2 : ~q2);
                while (m) {
                    int b = __ffs(m) - 1;
                    m &= m - 1;
                    int j = ln * 32 + b;
                    if (iou_ge(a4, gbox[(f + 1) * NBX + j]))
                        best = fmaxf(best, fmaxf(msn[j], 0.0f));
                }
            }
            #pragma unroll
            for (int off = 32; off > 0; off >>= 1)
                best = fmaxf(best, __shfl_down(best, off));
        }
        if (ln == 0) ms[rr] = actv ? __fadd_rn(scores[rr], best) : NEGV;
    }
}

// Traceback successor for a listed row when the LDS pool is unavailable.
// Returns next j, or -1 for "no link". Called by all 64 lanes of wave 0.
__device__ __attribute__((noinline))
int traceback_slow(int f, int cur, u32 enc, const float* msn, const u16* poolG,
                   const u32* clsbpool, const int* classes, const float4* gbox,
                   int use_pool, int ln) {
    float tv = -3.0e38f;
    int tj = 0x7fffffff;
    u32 slot = enc & 1023;
    bool recomp = true;
    if (slot != 1023 && use_pool) {
        int deg = (int)poolG[slot * PSTRIDE];
        if (deg != (int)DEG_RECOMP) {
            recomp = false;
            for (int q = ln; q < deg; q += 64) {
                int j = (int)poolG[slot * PSTRIDE + 1 + q];
                float m = msn[j];
                if (m != NEGV && (m > tv || (m == tv && j < tj))) { tv = m; tj = j; }
            }
        }
    }
    if (recomp && ln < 32) {
        int ca = classes[f * NBX + cur];
        float4 a4 = gbox[f * NBX + cur];
        const u32* cf = &clsbpool[f * 96];
        u32 q0 = cf[ln], q1 = cf[32 + ln], q2 = cf[64 + ln];
        u32 m = ((ca & 1) ? q0 : ~q0) & ((ca & 2) ? q1 : ~q1) & ((ca & 4) ? q2 : ~q2);
        while (m) {
            int b = __ffs(m) - 1;
            m &= m - 1;
            int j = ln * 32 + b;
            float mv = msn[j];
            if (mv != NEGV && iou_ge(a4, gbox[(f + 1) * NBX + j])) {
                if (mv > tv || (mv == tv && j < tj)) { tv = mv; tj = j; }
            }
        }
    }
    #pragma unroll
    for (int off = 32; off > 0; off >>= 1) {
        float ov = __shfl_down(tv, off);
        int   oj = __shfl_down(tj, off);
        if (ov > tv || (ov == tv && oj < tj)) { tv = ov; tj = oj; }
    }
    tv = __shfl(tv, 0);
    tj = __shfl(tj, 0);
    return (tv < -1.0e37f) ? -1 : tj;
}

// csr row encoding (u32): top 2 bits = cnt.
//   inline (cnt<=3): (cnt<<30)|(j2<<20)|(j1<<10)|j0 ascending -> j0!=j1 if cnt==3
//   listed: (3<<30)|(halfoff<<20)|(slot<<10)|slot, slot<OVTOT  (halfoff: LDS pool)
//   rescan: slot field == 1023 (slot budget exhausted; ~never)
// LDS pool row at poolL[2*halfoff]: [deg, score_lo, score_hi, j0..j_{deg-1}] (asc)
__global__ __launch_bounds__(1024) void seqnms(const float4* __restrict__ gbox,
                                               const float* __restrict__ scores,
                                               const int* __restrict__ classes,
                                               float* __restrict__ out,
                                               u16* __restrict__ poolG,
                                               const int use_pool) {
    __shared__ float4 seqbox[NFR];      // 128
    __shared__ float ms[NTOT];          // 32768
    __shared__ u32 csr[NROW];           // 28672
    __shared__ u32 clsbpool[672];       // 2688: class bitplanes f=1..7, then LDS pool
    __shared__ u32 ostart[8];
    __shared__ u32 ofill[7];
    __shared__ u32 ocnt[7];
    __shared__ float redv[16];
    __shared__ int   redi[16];
    __shared__ int   sel_sh[NFR];
    __shared__ int   seqcls[NFR];
    __shared__ float avg_sh;
    __shared__ int   valid_sh, done_sh, ldsflag;
    __shared__ u16 ovl[OVTOT];          // 256: listed row ids (column index)
    __shared__ u16 offsets[OVTOT];      // 256: staged degs, then halfoffs
    __shared__ u8  ovact[OVTOT];        // 128: activity, unique owner each
    // total ~65.2 KB <= 65536

    const int t = threadIdx.x, gw = t >> 6, ln = t & 63;
    u16* poolL = (u16*)clsbpool;        // valid only when ldsflag (bitplanes dead)

    float psc[NFR]; int pcl[NFR]; float4 pbx[NFR];
    #pragma unroll
    for (int f = 0; f < NFR; ++f) {
        psc[f] = scores[f * NBX + t];
        pcl[f] = classes[f * NBX + t];
        pbx[f] = gbox[f * NBX + t];
        out[f * NBX + t] = psc[f];      // identity part of the reference output
    }
    if (t < 7) { ocnt[t] = 0; ofill[t] = 0; }
    if (t < OVTOT) ovact[t] = 1;
    if (t == 0) { done_sh = 0; ldsflag = 0; }

    // ---- class bitplanes for frames 1..7 (clsbpool[(f)*96 + p*32 + w]) ----
    if (t < 224) {
        int fr = (t >> 5) + 1, w = t & 31;
        u32 p0 = 0, p1 = 0, p2 = 0;
        for (int b = 0; b < 32; ++b) {
            int c = classes[fr * NBX + w * 32 + b];
            p0 |= (u32)(c & 1) << b;
            p1 |= (u32)((c >> 1) & 1) << b;
            p2 |= (u32)((c >> 2) & 1) << b;
        }
        clsbpool[(fr - 1) * 96 + w] = p0;
        clsbpool[(fr - 1) * 96 + 32 + w] = p1;
        clsbpool[(fr - 1) * 96 + 64 + w] = p2;
    }
    __syncthreads();

    // ---- CSR pass 1: inline rows + overflow counting (ascending j) ----
    for (int f = 0; f < 7; ++f) {
        int r = f * NBX + t;
        int ca = pcl[f];
        float4 a4 = pbx[f];
        u32 cnt = 0, j0 = 0, j1 = 0, j2 = 0;
        const u32* cf = &clsbpool[f * 96];
        for (int w = 0; w < 32; ++w) {
            u32 q0 = cf[w], q1 = cf[32 + w], q2 = cf[64 + w];
            u32 m = ((ca & 1) ? q0 : ~q0) & ((ca & 2) ? q1 : ~q1) & ((ca & 4) ? q2 : ~q2);
            while (m) {
                int b = __ffs(m) - 1;
                m &= m - 1;
                int j = w * 32 + b;
                if (iou_ge(a4, gbox[(f + 1) * NBX + j])) {
                    if (cnt == 0) j0 = j; else if (cnt == 1) j1 = j; else if (cnt == 2) j2 = j;
                    ++cnt;
                }
            }
        }
        if (cnt <= 3) csr[r] = (cnt << 30) | (j2 << 20) | (j1 << 10) | j0;
        else { atomicAdd(&ocnt[f], 1u); csr[r] = ENC_PENDING; }
    }
    __syncthreads();
    if (t == 0) {
        u32 s = 0;
        for (int f = 0; f < 7; ++f) { ostart[f] = s; s += ocnt[f]; }
        ostart[7] = s;
    }
    __syncthreads();
    // ---- pass 1b: assign slots ----
    for (int f = 0; f < 7; ++f) {
        int r = f * NBX + t;
        if (csr[r] == ENC_PENDING) {
            u32 slot = ostart[f] + atomicAdd(&ofill[f], 1u);
            if (slot < OVTOT) { ovl[slot] = (u16)t; csr[r] = (3u << 30) | (slot << 10) | slot; }
            else csr[r] = ENC_RESCAN;
        }
    }
    __syncthreads();
    const int totalL = (int)((ostart[7] > OVTOT) ? OVTOT : ostart[7]);
    const bool slots_ok = ((int)ostart[7] <= OVTOT);
    // ---- pass 2: materialize neighbor lists into the GLOBAL pool ----
    if (use_pool) {
        for (int s = gw; s < totalL; s += 16) {
            int f = 0;
            while (s >= (int)ostart[f + 1]) ++f;
            int i = ovl[s];
            int ca = classes[f * NBX + i];
            float4 a4 = gbox[f * NBX + i];
            u32 mym = 0;
            if (ln < 32) {
                const u32* cf = &clsbpool[f * 96];
                u32 q0 = cf[ln], q1 = cf[32 + ln], q2 = cf[64 + ln];
                u32 m = ((ca & 1) ? q0 : ~q0) & ((ca & 2) ? q1 : ~q1) & ((ca & 4) ? q2 : ~q2);
                while (m) {
                    int b = __ffs(m) - 1;
                    m &= m - 1;
                    if (iou_ge(a4, gbox[(f + 1) * NBX + ln * 32 + b])) mym |= 1u << b;
                }
            }
            int c = __popc(mym), inc = c;
            for (int off = 1; off < 64; off <<= 1) {
                int v = __shfl_up(inc, off);
                if (ln >= off) inc += v;
            }
            int deg = __shfl(inc, 63);
            int base = inc - c;
            if (deg <= PSTRIDE - 1) {
                if (ln == 0) poolG[s * PSTRIDE] = (u16)deg;
                if (ln < 32) {
                    u32 m = mym; int idx = base;
                    while (m) {
                        int b = __ffs(m) - 1;
                        m &= m - 1;
                        poolG[s * PSTRIDE + 1 + idx++] = (u16)(ln * 32 + b);
                    }
                }
            } else if (ln == 0) poolG[s * PSTRIDE] = (u16)DEG_RECOMP;
        }
    }
    __syncthreads();
    // ---- LDS pool build: stage degs, prefix offsets, copy rows ----
    if (use_pool && slots_ok) {
        if (t < totalL) offsets[t] = poolG[t * PSTRIDE];
        __syncthreads();
        if (t == 0) {
            int ok = 1;
            u32 off = 0;
            for (int s = 0; s < totalL; ++s) {
                u32 d = offsets[s];
                u32 need = (3u + d + 1u) & ~1u;
                if (d == (u32)DEG_RECOMP || off + need > LPOOLCAP) { ok = 0; break; }
                offsets[s] = (u16)(off >> 1);     // halfoff
                off += need;
            }
            ldsflag = ok;
        }
    }
    __syncthreads();
    if (ldsflag) {
        // owner threads stamp halfoff into their listed rows' enc
        #pragma unroll
        for (int f = 0; f < 7; ++f) {
            u32 p = csr[f * NBX + t];
            if ((p >> 30) == 3u && (p & 1023) == ((p >> 10) & 1023) && (p & 1023) != 1023)
                csr[f * NBX + t] = p | ((u32)offsets[p & 1023] << 20);
        }
        // waves copy rows global -> LDS (bitplanes dead from here on)
        for (int s = gw; s < totalL; s += 16) {
            int f = 0;
            while (s >= (int)ostart[f + 1]) ++f;
            int i = ovl[s];
            int deg = (int)poolG[s * PSTRIDE];
            int base = ((int)offsets[s]) * 2;
            for (int q = ln; q < deg; q += 64)
                poolL[base + 3 + q] = poolG[s * PSTRIDE + 1 + q];
            if (ln == 0) {
                poolL[base] = (u16)deg;
                u32 sb = __float_as_uint(scores[f * NBX + i]);
                poolL[base + 1] = (u16)(sb & 0xFFFF);
                poolL[base + 2] = (u16)(sb >> 16);
            }
        }
    }
    __syncthreads();

    // ---- iteration-invariant registers ----
    u32 pc[7]; u32 lmask = 0;
    #pragma unroll
    for (int f = 0; f < 7; ++f) {
        u32 p = csr[f * NBX + t];
        pc[f] = p;
        if ((p >> 30) == 3u && ((p >> 10) & 1023) == (p & 1023) && (p & 1023) != 1023)
            lmask |= 1u << f;
    }
    int os[8];
    #pragma unroll
    for (int f = 0; f < 8; ++f) {
        int v = (int)ostart[f]; if (v > OVTOT) v = OVTOT;
        os[f] = __builtin_amdgcn_readfirstlane(v);
    }
    const int ldsp = __builtin_amdgcn_readfirstlane(ldsflag);
    u32 act = 0xFF;
    float ms7 = psc[7];
    ms[7 * NBX + t] = ms7;
    __syncthreads();

    // ---- 48 greedy extractions. active(f,i) <=> ms[f][i] != NEGV; active => ms>=0.
    //      Hot loop is all-LDS (no vmcnt at barriers) and I-cache-compact. ----
    for (int it = 0; it < MAXS; ++it) {
        float bv = ms7; int bi = 7 * NBX + t;
        #pragma unroll
        for (int f = 6; f >= 0; --f) {
            const float* msn = &ms[(f + 1) * NBX];
            const int r = f * NBX + t;
            const u32 p = pc[f];
            const u32 c = p >> 30, j0 = p & 1023, j1 = (p >> 10) & 1023;
            if (!((c == 3u) && (j0 == j1))) {           // inline (vast majority)
                float v = NEGV;
                if ((act >> f) & 1) {
                    float best = 0.0f;                  // == ref max(where(eff,ms_next,0))
                    if (c >= 1) best = fmaxf(best, fmaxf(msn[j0], 0.0f));
                    if (c >= 2) best = fmaxf(best, fmaxf(msn[j1], 0.0f));
                    if (c >= 3) best = fmaxf(best, fmaxf(msn[(p >> 20) & 1023], 0.0f));
                    v = __fadd_rn(psc[f], best);
                }
                ms[r] = v;
                if (v > bv || (v == bv && r < bi)) { bv = v; bi = r; }
            } else if (j0 == 1023) {                    // rescan (~never)
                float v = NEGV;
                if ((act >> f) & 1)
                    v = __fadd_rn(psc[f], rescan_best(&clsbpool[f * 96], msn,
                                                      gbox + (f + 1) * NBX, pcl[f], pbx[f]));
                ms[r] = v;
                if (v > bv || (v == bv && r < bi)) { bv = v; bi = r; }
            }
            // phase B: listed rows, one wave each
            if (os[f] < os[f + 1]) {
                if (ldsp) {
                    for (int s = os[f] + gw; s < os[f + 1]; s += 16) {
                        int i = ovl[s];
                        int rr = f * NBX + i;
                        int base = (int)((csr[rr] >> 20) & 1023) * 2;
                        bool actv = ovact[s] != 0;
                        float best = 0.0f;
                        if (actv) {
                            int deg = poolL[base];
                            for (int q = ln; q < deg; q += 64)
                                best = fmaxf(best, fmaxf(msn[poolL[base + 3 + q]], 0.0f));
                            #pragma unroll
                            for (int off = 32; off > 0; off >>= 1)
                                best = fmaxf(best, __shfl_down(best, off));
                        }
                        if (ln == 0) {
                            u32 sb = (u32)poolL[base + 1] | ((u32)poolL[base + 2] << 16);
                            ms[rr] = actv ? __fadd_rn(__uint_as_float(sb), best) : NEGV;
                        }
                    }
                } else {
                    phaseB_slow(f, ms, msn, ovl, ovact, clsbpool, poolG,
                                scores, classes, gbox, os[f], os[f + 1], gw, ln, use_pool);
                }
            }
            __syncthreads();
        }

        // ---- listed fix-up + per-wave argmax reduce ----
        #pragma unroll
        for (int f = 0; f < 7; ++f) if ((lmask >> f) & 1) {
            int r = f * NBX + t; float v = ms[r];
            if (v > bv || (v == bv && r < bi)) { bv = v; bi = r; }
        }
        #pragma unroll
        for (int off = 32; off > 0; off >>= 1) {
            float ov = __shfl_down(bv, off); int oi = __shfl_down(bi, off);
            if (ov > bv || (ov == bv && oi < bi)) { bv = ov; bi = oi; }
        }
        if (ln == 0) { redv[gw] = bv; redi[gw] = bi; }
        __syncthreads();

        // ---- wave 0: final reduce + traceback + stats ----
        if (t < 64) {
            float v = (ln < 16) ? redv[ln] : -3.0e38f;
            int i0 = (ln < 16) ? redi[ln] : 0x7fffffff;
            #pragma unroll
            for (int off = 8; off > 0; off >>= 1) {
                float ov = __shfl_down(v, off); int oi = __shfl_down(i0, off);
                if (ov > v || (ov == v && oi < i0)) { v = ov; i0 = oi; }
            }
            v = __shfl(v, 0); i0 = __shfl(i0, 0);
            const float bestval = v;
            const int fstar = i0 >> 10, istar = i0 & (NBX - 1);
            if (ln < NFR) sel_sh[ln] = -1;
            int cur = istar;
            for (int f = fstar; f < NFR; ++f) {         // breaks wave-uniform
                if (ln == 0) sel_sh[f] = cur;
                if (f == 7) break;                      // adj_pad[7] all-zero
                u32 p = csr[f * NBX + cur];
                u32 c = p >> 30, j0 = p & 1023, j1 = (p >> 10) & 1023;
                const float* msn = &ms[(f + 1) * NBX];
                if (!((c == 3u) && (j0 == j1))) {       // inline: all-lane redundant
                    float tb = -3.0e38f; int tj = -1;   // ascending + strict >
                    if (c >= 1) { float m = msn[j0]; if (m != NEGV) { tb = m; tj = (int)j0; } }
                    if (c >= 2) { float m = msn[j1]; if (m != NEGV && m > tb) { tb = m; tj = (int)j1; } }
                    if (c >= 3) { int j2 = (int)((p >> 20) & 1023); float m = msn[j2];
                                  if (m != NEGV && m > tb) { tb = m; tj = j2; } }
                    if (tj < 0) break;                  // !has_link
                    cur = tj;
                } else if (ldsp && j0 != 1023) {        // LDS pool (expected path)
                    int base = (int)((p >> 20) & 1023) * 2;
                    int deg = poolL[base];
                    float tv = -3.0e38f; int tj = 0x7fffffff;
                    for (int q = ln; q < deg; q += 64) {
                        int j = poolL[base + 3 + q];
                        float m = msn[j];
                        if (m != NEGV && (m > tv || (m == tv && j < tj))) { tv = m; tj = j; }
                    }
                    #pragma unroll
                    for (int off = 32; off > 0; off >>= 1) {
                        float ov = __shfl_down(tv, off); int oj = __shfl_down(tj, off);
                        if (ov > tv || (ov == tv && oj < tj)) { tv = ov; tj = oj; }
                    }
                    tv = __shfl(tv, 0); tj = __shfl(tj, 0);
                    if (tv < -1.0e37f) break;
                    cur = tj;
                } else {
                    int nj = traceback_slow(f, cur, p, msn, poolG, clsbpool,
                                            classes, gbox, use_pool, ln);
                    if (nj < 0) break;
                    cur = nj;
                }
            }
            float sv = 0.0f; int cc = 0;
            if (ln < NFR) {
                int sj = sel_sh[ln];
                if (sj >= 0) {
                    sv = scores[ln * NBX + sj]; cc = 1;
                    seqbox[ln] = gbox[ln * NBX + sj];
                    seqcls[ln] = classes[ln * NBX + sj];
                }
            }
            #pragma unroll
            for (int off = 4; off > 0; off >>= 1) {
                sv = __fadd_rn(sv, __shfl_down(sv, off));
                cc += __shfl_down(cc, off);
            }
            if (ln == 0) {
                avg_sh = __fdiv_rn(sv, (float)cc);      // cc >= 1 always
                bool ok = (cc > 1) && (bestval > 0.0f);
                valid_sh = (ok && !done_sh) ? 1 : 0;
                if (!ok) done_sh = 1;
            }
        }
        __syncthreads();

        // ---- suppression + state publish + out writes (only when valid) ----
        if (valid_sh) {
            #pragma unroll
            for (int f = 0; f < NFR; ++f) {
                int sj = sel_sh[f];
                if (sj < 0) continue;                   // frame_in false
                if (pcl[f] != seqcls[f]) continue;
                if (iou_ge(seqbox[f], pbx[f])) act &= ~(1u << f);
            }
            #pragma unroll
            for (int f = 0; f < 7; ++f) if ((lmask >> f) & 1)
                ovact[pc[f] & 1023] = (u8)((act >> f) & 1);  // unique owner
            ms7 = (act & 0x80) ? psc[7] : NEGV;
            ms[7 * NBX + t] = ms7;                      // next iteration's DP init
            if (t < NFR) {
                int sj = sel_sh[t];
                if (sj >= 0) out[t * NBX + sj] = avg_sh;
            }
        }
        __syncthreads();
        if (done_sh) break;   // uniform; remaining reference iterations are no-ops
    }
}

extern "C" void kernel_launch(void* const* d_in, const int* in_sizes, int n_in,
                              void* d_out, int out_size, void* d_ws, size_t ws_size,
                              hipStream_t stream) {
    const float4* boxes = (const float4*)d_in[0];     // (8,1024,4) float32
    const float* scores = (const float*)d_in[1];      // (8,1024) float32
    const int* classes = (const int*)d_in[2];         // (8,1024) int32
    float* out = (float*)d_out;                       // (8,1024) float32
    u16* pool = (u16*)d_ws;
    const int use_pool =
        (d_ws != nullptr && ws_size >= (size_t)(OVTOT * PSTRIDE * 2)) ? 1 : 0;

    seqnms<<<1, 1024, 0, stream>>>(boxes, scores, classes, out, pool, use_pool);
}